// Round 3
// baseline (93.224 us; speedup 1.0000x reference)
//
#include <hip/hip_runtime.h>
#include <cstdint>

// SingleConstFilteredNormalized: y[i,j] = (x[i,j]!=0) ? f / (f*cnt_i) : 0,
// cnt_i = #nonzeros in row i; safe=1 when f*cnt==0. B=16384, N=4096, fp32.
// Memory-bound: 256MiB read + 256MiB write (5.88 TB/s achieved in R2).
// One WAVE per row, 2 rows per wave via grid-stride, software-pipelined:
// row r+1's loads are issued before row r's reduce+store, so the wave keeps
// a full load queue across the reduce bubble. No LDS, no __syncthreads.

#define NCOL 4096
#define NV4  (NCOL / 4)       // 1024 float4 per row
#define BLK  256              // 4 waves per block
#define WPB  4                // waves per block

typedef float f4 __attribute__((ext_vector_type(4)));

__device__ __forceinline__ uint64_t load_row_mask(const f4* __restrict__ xr, int lane) {
    uint64_t mask = 0;
    #pragma unroll
    for (int k = 0; k < 16; ++k) {
        f4 v = __builtin_nontemporal_load(xr + lane + k * 64);
        uint64_t m = 0;
        m |= (v.x != 0.0f) ? 1ull : 0ull;
        m |= (v.y != 0.0f) ? 2ull : 0ull;
        m |= (v.z != 0.0f) ? 4ull : 0ull;
        m |= (v.w != 0.0f) ? 8ull : 0ull;
        mask |= m << (k * 4);
    }
    return mask;
}

__device__ __forceinline__ void store_row(f4* __restrict__ yr, int lane,
                                          uint64_t mask, float fv) {
    int c = __popcll(mask);
    #pragma unroll
    for (int off = 32; off > 0; off >>= 1)
        c += __shfl_xor(c, off);
    const float rs  = fv * (float)c;
    const float val = fv / ((rs != 0.0f) ? rs : 1.0f);
    #pragma unroll
    for (int k = 0; k < 16; ++k) {
        f4 o;
        o.x = ((mask >> (k * 4 + 0)) & 1ull) ? val : 0.0f;
        o.y = ((mask >> (k * 4 + 1)) & 1ull) ? val : 0.0f;
        o.z = ((mask >> (k * 4 + 2)) & 1ull) ? val : 0.0f;
        o.w = ((mask >> (k * 4 + 3)) & 1ull) ? val : 0.0f;
        __builtin_nontemporal_store(o, yr + lane + k * 64);
    }
}

__global__ __launch_bounds__(BLK)
void filt_norm_kernel(const float* __restrict__ x,
                      const float* __restrict__ f,
                      float* __restrict__ y,
                      int nrows) {
    const int lane  = threadIdx.x & 63;
    const int wid   = threadIdx.x >> 6;
    const int wave0 = blockIdx.x * WPB + wid;     // first row for this wave
    const int wstep = gridDim.x * WPB;            // total waves
    const float fv = f[0];

    int row = wave0;
    if (row >= nrows) return;

    // Pipeline: issue row's loads; while its reduce/store runs, next row's
    // loads are already in flight.
    uint64_t mask = load_row_mask((const f4*)x + (size_t)row * NV4, lane);
    for (int next = row + wstep; next < nrows; next += wstep) {
        uint64_t nmask = load_row_mask((const f4*)x + (size_t)next * NV4, lane);
        store_row((f4*)y + (size_t)row * NV4, lane, mask, fv);
        mask = nmask;
        row  = next;
    }
    store_row((f4*)y + (size_t)row * NV4, lane, mask, fv);
}

extern "C" void kernel_launch(void* const* d_in, const int* in_sizes, int n_in,
                              void* d_out, int out_size, void* d_ws, size_t ws_size,
                              hipStream_t stream) {
    // inputs: d_in[0]=t (unused scalar), d_in[1]=x [B,N] f32, d_in[2]=f [1] f32
    const float* x = (const float*)d_in[1];
    const float* f = (const float*)d_in[2];
    float*       y = (float*)d_out;
    const int nrows = in_sizes[1] / NCOL;

    // 2048 blocks * 4 waves = 8192 waves ~= full residency; 2 rows per wave.
    const int grid = 2048;
    filt_norm_kernel<<<grid, BLK, 0, stream>>>(x, f, y, nrows);
}

// Round 4
// 91.379 us; speedup vs baseline: 1.0202x; 1.0202x over previous
//
#include <hip/hip_runtime.h>
#include <cstdint>

// SingleConstFilteredNormalized: y[i,j] = (x[i,j]!=0) ? f / (f*cnt_i) : 0,
// cnt_i = #nonzeros in row i; safe=1 when f*cnt==0. B=16384, N=4096, fp32.
// Memory-bound: 256MiB read + 256MiB write. One WAVE per row: no LDS, no
// __syncthreads; row compressed to a 64-bit per-lane mask so load registers
// retire immediately (low VGPR -> high occupancy, deep load overlap).
// R2 measured 91.3us = 5.88 TB/s = 93.5% of D2D copy ceiling (6.29 TB/s).
// R3's 2-row software pipeline regressed (93.2us) -> HBM roofline; keep simple.

#define NCOL 4096
#define NV4  (NCOL / 4)       // 1024 float4 per row
#define BLK  256              // 4 waves per block
#define WPB  4                // waves (rows) per block

typedef float f4 __attribute__((ext_vector_type(4)));

__global__ __launch_bounds__(BLK)
void filt_norm_kernel(const float* __restrict__ x,
                      const float* __restrict__ f,
                      float* __restrict__ y,
                      int nrows) {
    const int lane = threadIdx.x & 63;
    const int wid  = threadIdx.x >> 6;
    const int row  = blockIdx.x * WPB + wid;
    if (row >= nrows) return;

    const float fv = f[0];
    const f4* __restrict__ xr = (const f4*)x + (size_t)row * NV4;
    f4*       __restrict__ yr = (f4*)y       + (size_t)row * NV4;

    // 16 coalesced float4 loads per lane; compress each to 4 mask bits.
    uint64_t mask = 0;
    #pragma unroll
    for (int k = 0; k < 16; ++k) {
        f4 v = __builtin_nontemporal_load(xr + lane + k * 64);
        uint64_t m = 0;
        m |= (v.x != 0.0f) ? 1ull : 0ull;
        m |= (v.y != 0.0f) ? 2ull : 0ull;
        m |= (v.z != 0.0f) ? 4ull : 0ull;
        m |= (v.w != 0.0f) ? 8ull : 0ull;
        mask |= m << (k * 4);
    }

    // Wave-64 butterfly reduce of the nonzero count.
    int c = __popcll(mask);
    #pragma unroll
    for (int off = 32; off > 0; off >>= 1)
        c += __shfl_xor(c, off);

    const float rs  = fv * (float)c;            // == reference row_sum (fp-exact enough)
    const float val = fv / ((rs != 0.0f) ? rs : 1.0f);

    // Masked streaming write from the bit mask.
    #pragma unroll
    for (int k = 0; k < 16; ++k) {
        f4 o;
        o.x = ((mask >> (k * 4 + 0)) & 1ull) ? val : 0.0f;
        o.y = ((mask >> (k * 4 + 1)) & 1ull) ? val : 0.0f;
        o.z = ((mask >> (k * 4 + 2)) & 1ull) ? val : 0.0f;
        o.w = ((mask >> (k * 4 + 3)) & 1ull) ? val : 0.0f;
        __builtin_nontemporal_store(o, yr + lane + k * 64);
    }
}

extern "C" void kernel_launch(void* const* d_in, const int* in_sizes, int n_in,
                              void* d_out, int out_size, void* d_ws, size_t ws_size,
                              hipStream_t stream) {
    // inputs: d_in[0]=t (unused scalar), d_in[1]=x [B,N] f32, d_in[2]=f [1] f32
    const float* x = (const float*)d_in[1];
    const float* f = (const float*)d_in[2];
    float*       y = (float*)d_out;
    const int nrows = in_sizes[1] / NCOL;

    const int grid = (nrows + WPB - 1) / WPB;   // one wave per row
    filt_norm_kernel<<<grid, BLK, 0, stream>>>(x, f, y, nrows);
}